// Round 1
// 566.010 us; speedup vs baseline: 1.0178x; 1.0178x over previous
//
#include <hip/hip_runtime.h>
#include <hip/hip_fp16.h>

// 2-branch PolyConv GNN + MLP head. float32, int32 indices.
// f_k = L^k h, L(f) = f - dinv*S(f*dinv). Filters = linear combos of f_0,f_1,f_2:
//   ortho: o0 = 3f0-3f1+0.75f2, o1 = 3f1-1.5f2, o2 = 0.75f2
//   sim:   all three = 4(f0+f1+f2)
// R8 changes vs R7:
//  (1) fp16 shadow buffers (h16/g16 in d_ws) for the GATHERED operand only;
//      own-row reads, accumulation, fixup stay fp32. Halves gather fetch bytes
//      and halves the L2 footprint (12.8 -> 6.4 MB/graph vs 4 MB/XCD L2).
//  (2) theta-combine fused into hop2 (hop2 gathers from ws, so hall rows are
//      private per-wave in hop2 -> write o0/o1/o2 (or ss) directly). Deletes
//      combine_kernel (~150 MB streamed).
//  (3) CSR build: merged count+fill launches (one grid over E+Es); fill bumps
//      row[d] itself (row becomes exclusive-prefix shifted by one; readers use
//      [d? row[d-1]:0, row[d]) ) -> second memset + 2 dispatches gone.
//  Fallback: if ws_size can't hold fp16 shadows, old fp32-gather path + combine.
// hall slots (stride 384): ortho f0/f1/f2 -> 0/64/128, sim -> 192/256/320.
// dinv (2N f32) lives in logits region (overwritten by MLP last).
// d_ws: row_o[N+1] row_s[N+1] cnt[2N] esrc_o[E] esrc_s[Es] part[2B]
//       h16_o[N*64] h16_s[N*64] g16_o[N*64] g16_s[N*64]  (halves)

__global__ __launch_bounds__(256) void count2_kernel(
    const int* __restrict__ dst, const int* __restrict__ sim_dst,
    int* __restrict__ cnt, int N, int E, int Es) {
    int e = blockIdx.x * 256 + threadIdx.x;
    if (e < E) atomicAdd(&cnt[dst[e]], 1);
    else if (e < E + Es) atomicAdd(&cnt[N + sim_dst[e - E]], 1);
}

// Phase 1: per-1024-chunk sums. grid = 2*B, cnt = [graph0 N | graph1 N].
__global__ __launch_bounds__(256) void scan_p1(const int* __restrict__ cnt,
                                               int* __restrict__ part, int N, int B) {
    int g = blockIdx.x / B, c = blockIdx.x - g * B;
    const int* p = cnt + (long)g * N;
    int tid = threadIdx.x, base = c << 10;
    int s = 0;
    #pragma unroll
    for (int q = 0; q < 4; ++q) {
        int i = base + q * 256 + tid;
        if (i < N) s += p[i];
    }
    #pragma unroll
    for (int off = 32; off > 0; off >>= 1) s += __shfl_down(s, off);
    __shared__ int ws[4];
    if ((tid & 63) == 0) ws[tid >> 6] = s;
    __syncthreads();
    if (tid == 0) part[blockIdx.x] = ws[0] + ws[1] + ws[2] + ws[3];
}

// Phase 2: exclusive scan of B partials per graph (B <= 64). grid = 2 x 64.
__global__ __launch_bounds__(64) void scan_p2(int* __restrict__ part,
                                              int* __restrict__ row_o,
                                              int* __restrict__ row_s, int N, int B) {
    int g = blockIdx.x, t = threadIdx.x;
    int v = (t < B) ? part[g * B + t] : 0;
    int inc = v;
    #pragma unroll
    for (int off = 1; off < 64; off <<= 1) {
        int u = __shfl_up(inc, off);
        if (t >= off) inc += u;
    }
    if (t < B) part[g * B + t] = inc - v;          // exclusive chunk offsets
    int total = __shfl(inc, 63);
    if (t == 0) (g == 0 ? row_o : row_s)[N] = total;
}

// Phase 3: block-local exclusive scan + chunk offset -> row; dinv fused.
__global__ __launch_bounds__(256) void scan_p3(const int* __restrict__ cnt,
                                               const int* __restrict__ part,
                                               int* __restrict__ row_o, int* __restrict__ row_s,
                                               float* __restrict__ dinv, int N, int B) {
    int g = blockIdx.x / B, c = blockIdx.x - g * B;
    int tid = threadIdx.x;
    int base = (c << 10) + tid * 4;
    const int* p = cnt + (long)g * N;
    int* row = (g == 0) ? row_o : row_s;
    float* dv = dinv + (long)g * N;
    int v[4];
    #pragma unroll
    for (int q = 0; q < 4; ++q) { int i = base + q; v[q] = (i < N) ? p[i] : 0; }
    int s = v[0] + v[1] + v[2] + v[3];
    int inc = s;
    #pragma unroll
    for (int off = 1; off < 64; off <<= 1) {
        int u = __shfl_up(inc, off);
        if ((tid & 63) >= off) inc += u;
    }
    __shared__ int wt[4];
    if ((tid & 63) == 63) wt[tid >> 6] = inc;
    __syncthreads();
    int wo = 0;
    for (int w = 0; w < (tid >> 6); ++w) wo += wt[w];
    int ex = part[blockIdx.x] + wo + inc - s;
    #pragma unroll
    for (int q = 0; q < 4; ++q) {
        int i = base + q;
        if (i < N) {
            row[i] = ex;
            dv[i] = rsqrtf((float)(v[q] > 1 ? v[q] : 1));
            ex += v[q];
        }
    }
}

// Merged fill for both graphs; uses row[d] itself as the cursor. Afterwards
// row[d] == original prefix[d+1], so readers use [d? row[d-1]:0, row[d]).
__global__ __launch_bounds__(256) void fill2_kernel(
    const int* __restrict__ src, const int* __restrict__ dst,
    const int* __restrict__ sim_src, const int* __restrict__ sim_dst,
    int* __restrict__ row_o, int* __restrict__ row_s,
    int* __restrict__ esrc_o, int* __restrict__ esrc_s, int E, int Es) {
    int e = blockIdx.x * 256 + threadIdx.x;
    if (e < E) {
        esrc_o[atomicAdd(&row_o[dst[e]], 1)] = src[e];
    } else if (e < E + Es) {
        int e2 = e - E;
        esrc_s[atomicAdd(&row_s[sim_dst[e2]], 1)] = sim_src[e2];
    }
}

// Tiled: out[node*384+off+j] = relu(x[node,:]@W[:,j] + b[j]); K=128.
// Also writes fp16 shadow copy h16[node*64+j] when h16 != nullptr.
__global__ __launch_bounds__(256) void in_gemm_kernel(
    const float* __restrict__ x, const float* __restrict__ W,
    const float* __restrict__ b, float* __restrict__ out, int off,
    __half* __restrict__ h16, int n) {
    __shared__ float xs[64][132];
    __shared__ float Wf[128][68];
    int tid = threadIdx.x;
    int node0 = blockIdx.x * 64;
    const float4* wsrc = (const float4*)W;
    for (int i = tid; i < 2048; i += 256)
        *(float4*)&Wf[i >> 4][(i & 15) * 4] = wsrc[i];
    const float4* xsrc = (const float4*)x;
    for (int i = tid; i < 2048; i += 256) {
        int nl = i >> 5, c = i & 31;
        int node = node0 + nl;
        float4 v = make_float4(0.f, 0.f, 0.f, 0.f);
        if (node < n) v = xsrc[(long)node * 32 + c];
        *(float4*)&xs[nl][c * 4] = v;
    }
    __syncthreads();
    int tx = tid & 15, ty = tid >> 4;
    float acc[4][4] = {};
    #pragma unroll 2
    for (int k = 0; k < 128; k += 4) {
        float4 a[4], bb[4];
        #pragma unroll
        for (int i = 0; i < 4; ++i) a[i] = *(const float4*)&xs[ty * 4 + i][k];
        #pragma unroll
        for (int j = 0; j < 4; ++j) bb[j] = *(const float4*)&Wf[k + j][tx * 4];
        #pragma unroll
        for (int i = 0; i < 4; ++i) {
            acc[i][0] = fmaf(a[i].x, bb[0].x, acc[i][0]);
            acc[i][1] = fmaf(a[i].x, bb[0].y, acc[i][1]);
            acc[i][2] = fmaf(a[i].x, bb[0].z, acc[i][2]);
            acc[i][3] = fmaf(a[i].x, bb[0].w, acc[i][3]);
            acc[i][0] = fmaf(a[i].y, bb[1].x, acc[i][0]);
            acc[i][1] = fmaf(a[i].y, bb[1].y, acc[i][1]);
            acc[i][2] = fmaf(a[i].y, bb[1].z, acc[i][2]);
            acc[i][3] = fmaf(a[i].y, bb[1].w, acc[i][3]);
            acc[i][0] = fmaf(a[i].z, bb[2].x, acc[i][0]);
            acc[i][1] = fmaf(a[i].z, bb[2].y, acc[i][1]);
            acc[i][2] = fmaf(a[i].z, bb[2].z, acc[i][2]);
            acc[i][3] = fmaf(a[i].z, bb[2].w, acc[i][3]);
            acc[i][0] = fmaf(a[i].w, bb[3].x, acc[i][0]);
            acc[i][1] = fmaf(a[i].w, bb[3].y, acc[i][1]);
            acc[i][2] = fmaf(a[i].w, bb[3].z, acc[i][2]);
            acc[i][3] = fmaf(a[i].w, bb[3].w, acc[i][3]);
        }
    }
    float4 bias = *(const float4*)&b[tx * 4];
    #pragma unroll
    for (int i = 0; i < 4; ++i) {
        int node = node0 + ty * 4 + i;
        if (node >= n) break;
        float4 r;
        r.x = fmaxf(acc[i][0] + bias.x, 0.0f);
        r.y = fmaxf(acc[i][1] + bias.y, 0.0f);
        r.z = fmaxf(acc[i][2] + bias.z, 0.0f);
        r.w = fmaxf(acc[i][3] + bias.w, 0.0f);
        *(float4*)&out[(long)node * 384 + off + tx * 4] = r;
        if (h16) {
            __half hh[4];
            hh[0] = __float2half_rn(r.x);
            hh[1] = __float2half_rn(r.y);
            hh[2] = __float2half_rn(r.z);
            hh[3] = __float2half_rn(r.w);
            *(float2*)&h16[(long)node * 64 + tx * 4] = *(float2*)hh;
        }
    }
}

// Hop 1, both graphs merged. Gathers fp16 h16, own-row fp32 from hall.
// Writes f1 fp32 -> hall slot base+64 and fp16 shadow -> g16.
__global__ __launch_bounds__(256) void hop1_kernel(
    const int* __restrict__ row_o, const int* __restrict__ esrc_o, const float* __restrict__ dinv_o,
    const int* __restrict__ row_s, const int* __restrict__ esrc_s, const float* __restrict__ dinv_s,
    const __half* __restrict__ h16_o, const __half* __restrict__ h16_s,
    __half* __restrict__ g16_o, __half* __restrict__ g16_s,
    float* __restrict__ hall, int n, int nb) {
    int b = blockIdx.x;
    const int* row; const int* esrc; const float* dinv; const __half* h16; __half* g16; int base;
    if (b < nb) { row = row_o; esrc = esrc_o; dinv = dinv_o; h16 = h16_o; g16 = g16_o; base = 0; }
    else { b -= nb; row = row_s; esrc = esrc_s; dinv = dinv_s; h16 = h16_s; g16 = g16_s; base = 192; }
    int d = b * 4 + (threadIdx.x >> 6);
    if (d >= n) return;
    int lane = threadIdx.x & 63;
    int p = d ? row[d - 1] : 0;
    int end = row[d];
    long ob = (long)d * 384 + lane;
    float dd = dinv[d];           // issue own-data loads early, overlap gathers
    float f0 = hall[ob + base];
    float a0 = 0.f, a1 = 0.f, a2 = 0.f, a3 = 0.f;
    for (; p + 4 <= end; p += 4) {
        int s0 = esrc[p], s1 = esrc[p + 1], s2 = esrc[p + 2], s3 = esrc[p + 3];
        a0 = fmaf(__half2float(h16[(long)s0 * 64 + lane]), dinv[s0], a0);
        a1 = fmaf(__half2float(h16[(long)s1 * 64 + lane]), dinv[s1], a1);
        a2 = fmaf(__half2float(h16[(long)s2 * 64 + lane]), dinv[s2], a2);
        a3 = fmaf(__half2float(h16[(long)s3 * 64 + lane]), dinv[s3], a3);
    }
    for (; p < end; ++p) {
        int s = esrc[p];
        a0 = fmaf(__half2float(h16[(long)s * 64 + lane]), dinv[s], a0);
    }
    float acc = (a0 + a1) + (a2 + a3);
    float f1 = f0 - acc * dd;
    hall[ob + base + 64] = f1;
    g16[(long)d * 64 + lane] = __float2half_rn(f1);
}

// Hop 2 + fused theta-combine, both graphs merged. Gathers fp16 g16 (in ws),
// so every hall row is touched only by its own wave -> race-free overwrite.
__global__ __launch_bounds__(256) void hop2_kernel(
    const int* __restrict__ row_o, const int* __restrict__ esrc_o, const float* __restrict__ dinv_o,
    const int* __restrict__ row_s, const int* __restrict__ esrc_s, const float* __restrict__ dinv_s,
    const __half* __restrict__ g16_o, const __half* __restrict__ g16_s,
    float* __restrict__ hall, int n, int nb) {
    int b = blockIdx.x;
    bool ortho = b < nb;
    const int* row; const int* esrc; const float* dinv; const __half* g16; int base;
    if (ortho) { row = row_o; esrc = esrc_o; dinv = dinv_o; g16 = g16_o; base = 0; }
    else { b -= nb; row = row_s; esrc = esrc_s; dinv = dinv_s; g16 = g16_s; base = 192; }
    int d = b * 4 + (threadIdx.x >> 6);
    if (d >= n) return;
    int lane = threadIdx.x & 63;
    int p = d ? row[d - 1] : 0;
    int end = row[d];
    long ob = (long)d * 384 + lane;
    float dd = dinv[d];
    float f0 = hall[ob + base];
    float f1 = hall[ob + base + 64];
    float a0 = 0.f, a1 = 0.f, a2 = 0.f, a3 = 0.f;
    for (; p + 4 <= end; p += 4) {
        int s0 = esrc[p], s1 = esrc[p + 1], s2 = esrc[p + 2], s3 = esrc[p + 3];
        a0 = fmaf(__half2float(g16[(long)s0 * 64 + lane]), dinv[s0], a0);
        a1 = fmaf(__half2float(g16[(long)s1 * 64 + lane]), dinv[s1], a1);
        a2 = fmaf(__half2float(g16[(long)s2 * 64 + lane]), dinv[s2], a2);
        a3 = fmaf(__half2float(g16[(long)s3 * 64 + lane]), dinv[s3], a3);
    }
    for (; p < end; ++p) {
        int s = esrc[p];
        a0 = fmaf(__half2float(g16[(long)s * 64 + lane]), dinv[s], a0);
    }
    float acc = (a0 + a1) + (a2 + a3);
    float f2 = f1 - acc * dd;
    if (ortho) {
        hall[ob]       = 3.0f * f0 - 3.0f * f1 + 0.75f * f2;
        hall[ob + 64]  = 3.0f * f1 - 1.5f * f2;
        hall[ob + 128] = 0.75f * f2;
    } else {
        float ss = 4.0f * (f0 + f1 + f2);
        hall[ob + 192] = ss; hall[ob + 256] = ss; hall[ob + 320] = ss;
    }
}

// ---------- fallback path (ws too small for fp16 shadows) ----------
__global__ __launch_bounds__(256) void gather2_kernel(
    const int* __restrict__ row_o, const int* __restrict__ esrc_o, const float* __restrict__ dinv_o,
    const int* __restrict__ row_s, const int* __restrict__ esrc_s, const float* __restrict__ dinv_s,
    float* __restrict__ hall, int in_off_o, int in_off_s, int n, int nb) {
    int b = blockIdx.x;
    const int* row; const int* esrc; const float* dinv; int in_off;
    if (b < nb) { row = row_o; esrc = esrc_o; dinv = dinv_o; in_off = in_off_o; }
    else { b -= nb; row = row_s; esrc = esrc_s; dinv = dinv_s; in_off = in_off_s; }
    int d = b * 4 + (threadIdx.x >> 6);
    if (d >= n) return;
    int lane = threadIdx.x & 63;
    int p = d ? row[d - 1] : 0, end = row[d];
    const float* fin = hall + in_off;
    float a0 = 0.f, a1 = 0.f, a2 = 0.f, a3 = 0.f;
    for (; p + 4 <= end; p += 4) {
        int s0 = esrc[p], s1 = esrc[p + 1], s2 = esrc[p + 2], s3 = esrc[p + 3];
        a0 = fmaf(fin[(long)s0 * 384 + lane], dinv[s0], a0);
        a1 = fmaf(fin[(long)s1 * 384 + lane], dinv[s1], a1);
        a2 = fmaf(fin[(long)s2 * 384 + lane], dinv[s2], a2);
        a3 = fmaf(fin[(long)s3 * 384 + lane], dinv[s3], a3);
    }
    for (; p < end; ++p) {
        int s = esrc[p];
        a0 = fmaf(fin[(long)s * 384 + lane], dinv[s], a0);
    }
    float acc = (a0 + a1) + (a2 + a3);
    long ob = (long)d * 384 + lane;
    hall[ob + in_off + 64] = fin[ob] - acc * dinv[d];
}

__global__ __launch_bounds__(256) void combine_kernel(float* __restrict__ h, int nf) {
    int i = blockIdx.x * 256 + threadIdx.x;
    if (i >= nf) return;
    long ob = (long)(i >> 6) * 384 + (i & 63);
    float f0v = h[ob], f1v = h[ob + 64], f2v = h[ob + 128];
    h[ob]       = 3.0f * f0v - 3.0f * f1v + 0.75f * f2v;
    h[ob + 64]  = 3.0f * f1v - 1.5f * f2v;
    h[ob + 128] = 0.75f * f2v;
    float ss = 4.0f * (h[ob + 192] + h[ob + 256] + h[ob + 320]);
    h[ob + 192] = ss; h[ob + 256] = ss; h[ob + 320] = ss;
}
// -------------------------------------------------------------------

// logits = relu(h_all @ Wm1 + bm1) @ Wm2 + bm2. Tiled, K=384 in 3 chunks.
__global__ __launch_bounds__(256) void mlp_kernel(
    const float* __restrict__ hall, const float* __restrict__ Wm1,
    const float* __restrict__ bm1, const float* __restrict__ Wm2,
    const float* __restrict__ bm2, float* __restrict__ logits, int n) {
    __shared__ float xs[64][132];
    __shared__ float Wf[128][68];
    int tid = threadIdx.x;
    int node0 = blockIdx.x * 64;
    int tx = tid & 15, ty = tid >> 4;
    float acc[4][4] = {};
    const float4* wsrc = (const float4*)Wm1;
    const float4* hsrc = (const float4*)hall;
    for (int c = 0; c < 3; ++c) {
        __syncthreads();
        for (int i = tid; i < 2048; i += 256)
            *(float4*)&Wf[i >> 4][(i & 15) * 4] = wsrc[c * 2048 + i];
        for (int i = tid; i < 2048; i += 256) {
            int nl = i >> 5, cc = i & 31;
            int node = node0 + nl;
            float4 v = make_float4(0.f, 0.f, 0.f, 0.f);
            if (node < n) v = hsrc[(long)node * 96 + c * 32 + cc];
            *(float4*)&xs[nl][cc * 4] = v;
        }
        __syncthreads();
        #pragma unroll 2
        for (int k = 0; k < 128; k += 4) {
            float4 a[4], bb[4];
            #pragma unroll
            for (int i = 0; i < 4; ++i) a[i] = *(const float4*)&xs[ty * 4 + i][k];
            #pragma unroll
            for (int j = 0; j < 4; ++j) bb[j] = *(const float4*)&Wf[k + j][tx * 4];
            #pragma unroll
            for (int i = 0; i < 4; ++i) {
                acc[i][0] = fmaf(a[i].x, bb[0].x, acc[i][0]);
                acc[i][1] = fmaf(a[i].x, bb[0].y, acc[i][1]);
                acc[i][2] = fmaf(a[i].x, bb[0].z, acc[i][2]);
                acc[i][3] = fmaf(a[i].x, bb[0].w, acc[i][3]);
                acc[i][0] = fmaf(a[i].y, bb[1].x, acc[i][0]);
                acc[i][1] = fmaf(a[i].y, bb[1].y, acc[i][1]);
                acc[i][2] = fmaf(a[i].y, bb[1].z, acc[i][2]);
                acc[i][3] = fmaf(a[i].y, bb[1].w, acc[i][3]);
                acc[i][0] = fmaf(a[i].z, bb[2].x, acc[i][0]);
                acc[i][1] = fmaf(a[i].z, bb[2].y, acc[i][1]);
                acc[i][2] = fmaf(a[i].z, bb[2].z, acc[i][2]);
                acc[i][3] = fmaf(a[i].z, bb[2].w, acc[i][3]);
                acc[i][0] = fmaf(a[i].w, bb[3].x, acc[i][0]);
                acc[i][1] = fmaf(a[i].w, bb[3].y, acc[i][1]);
                acc[i][2] = fmaf(a[i].w, bb[3].z, acc[i][2]);
                acc[i][3] = fmaf(a[i].w, bb[3].w, acc[i][3]);
            }
        }
    }
    __syncthreads();
    float4 bias = *(const float4*)&bm1[tx * 4];
    #pragma unroll
    for (int i = 0; i < 4; ++i) {
        xs[ty * 4 + i][tx * 4 + 0] = fmaxf(acc[i][0] + bias.x, 0.0f);
        xs[ty * 4 + i][tx * 4 + 1] = fmaxf(acc[i][1] + bias.y, 0.0f);
        xs[ty * 4 + i][tx * 4 + 2] = fmaxf(acc[i][2] + bias.z, 0.0f);
        xs[ty * 4 + i][tx * 4 + 3] = fmaxf(acc[i][3] + bias.w, 0.0f);
    }
    __syncthreads();
    if (tid < 128) {
        int nl = tid >> 1, o = tid & 1;
        int node = node0 + nl;
        if (node < n) {
            float p = bm2[o];
            #pragma unroll 8
            for (int k = 0; k < 64; ++k) p = fmaf(xs[nl][k], Wm2[k * 2 + o], p);
            logits[(long)node * 2 + o] = p;
        }
    }
}

extern "C" void kernel_launch(void* const* d_in, const int* in_sizes, int n_in,
                              void* d_out, int out_size, void* d_ws, size_t ws_size,
                              hipStream_t stream) {
    const float* x     = (const float*)d_in[0];
    const float* sim_x = (const float*)d_in[1];
    const int* src     = (const int*)d_in[2];
    const int* dst     = (const int*)d_in[3];
    const int* sim_src = (const int*)d_in[4];
    const int* sim_dst = (const int*)d_in[5];
    const float* W1_o = (const float*)d_in[6];
    const float* b1_o = (const float*)d_in[7];
    const float* W1_s = (const float*)d_in[8];
    const float* b1_s = (const float*)d_in[9];
    const float* Wm1  = (const float*)d_in[10];
    const float* bm1  = (const float*)d_in[11];
    const float* Wm2  = (const float*)d_in[12];
    const float* bm2  = (const float*)d_in[13];

    const int N  = in_sizes[0] / 128;  // 50000
    const int E  = in_sizes[2];        // 800000
    const int Es = in_sizes[4];
    const int NF = N * 64;
    const int B  = (N + 1023) >> 10;   // chunks per graph (49; must be <= 64)

    float* hall = (float*)d_out;                 // N x 384
    float* lgt  = hall + (long)N * 384;          // N x 2
    float* dinv = lgt;                           // [dinv_o N | dinv_s N] until MLP
    float* dinv_o = dinv;
    float* dinv_s = dinv + N;

    int* row_o  = (int*)d_ws;          // N+1
    int* row_s  = row_o + (N + 1);     // N+1
    int* cnt    = row_s + (N + 1);     // 2N
    int* esrc_o = cnt + 2 * N;         // E
    int* esrc_s = esrc_o + E;          // Es
    int* part   = esrc_s + Es;         // 2B
    __half* h16_o = (__half*)(part + 2 * B);     // N*64 halves each
    __half* h16_s = h16_o + (long)N * 64;
    __half* g16_o = h16_s + (long)N * 64;
    __half* g16_s = g16_o + (long)N * 64;
    size_t need = (size_t)((char*)(g16_s + (long)N * 64) - (char*)d_ws);
    bool f16path = ws_size >= need;

    int nb4  = (N + 3) / 4;
    int nb64 = (N + 63) / 64;
    int nfb  = (NF + 255) / 256;
    int ebA  = (E + Es + 255) / 256;

    // ---- CSR build ----
    hipMemsetAsync(cnt, 0, (size_t)(2 * N) * sizeof(int), stream);
    count2_kernel<<<ebA, 256, 0, stream>>>(dst, sim_dst, cnt, N, E, Es);
    scan_p1<<<2 * B, 256, 0, stream>>>(cnt, part, N, B);
    scan_p2<<<2, 64, 0, stream>>>(part, row_o, row_s, N, B);
    scan_p3<<<2 * B, 256, 0, stream>>>(cnt, part, row_o, row_s, dinv, N, B);
    // fill bumps row[d] in place -> row becomes prefix shifted by one
    fill2_kernel<<<ebA, 256, 0, stream>>>(src, dst, sim_src, sim_dst,
                                          row_o, row_s, esrc_o, esrc_s, E, Es);

    // ---- input GEMMs: ortho -> slot 0, sim -> slot 192 (+ fp16 shadows) ----
    in_gemm_kernel<<<nb64, 256, 0, stream>>>(x, W1_o, b1_o, hall, 0,
                                             f16path ? h16_o : (__half*)nullptr, N);
    in_gemm_kernel<<<nb64, 256, 0, stream>>>(sim_x, W1_s, b1_s, hall, 192,
                                             f16path ? h16_s : (__half*)nullptr, N);

    if (f16path) {
        // hop1: gather fp16 h -> f1 (fp32 slot base+64, fp16 shadow g16)
        hop1_kernel<<<2 * nb4, 256, 0, stream>>>(row_o, esrc_o, dinv_o,
                                                 row_s, esrc_s, dinv_s,
                                                 h16_o, h16_s, g16_o, g16_s,
                                                 hall, N, nb4);
        // hop2 + fused theta combine (writes final hall slots)
        hop2_kernel<<<2 * nb4, 256, 0, stream>>>(row_o, esrc_o, dinv_o,
                                                 row_s, esrc_s, dinv_s,
                                                 g16_o, g16_s, hall, N, nb4);
    } else {
        gather2_kernel<<<2 * nb4, 256, 0, stream>>>(row_o, esrc_o, dinv_o,
                                                    row_s, esrc_s, dinv_s,
                                                    hall, 0, 192, N, nb4);
        gather2_kernel<<<2 * nb4, 256, 0, stream>>>(row_o, esrc_o, dinv_o,
                                                    row_s, esrc_s, dinv_s,
                                                    hall, 64, 256, N, nb4);
        combine_kernel<<<nfb, 256, 0, stream>>>(hall, NF);
    }

    // ---- MLP head (overwrites dinv stash with logits) ----
    mlp_kernel<<<nb64, 256, 0, stream>>>(hall, Wm1, bm1, Wm2, bm2, lgt, N);
}